// Round 5
// baseline (80.457 us; speedup 1.0000x reference)
//
#include <hip/hip_runtime.h>
#include <hip/hip_cooperative_groups.h>
#include <math.h>

namespace cg = cooperative_groups;

// Gaussian map generator: out[z,y,x] = sum_a amp[a] * exp(-c * |r_voxel - r_atom|^2)
// c = 1/(2 sigma^2), sigma = resolution/(sqrt(2) pi).  res=2 -> c~2.467.
//
// Round 5: fuse zero + scatter into ONE cooperative kernel with a grid sync.
// Round 4 showed zero ~2us + scatter ~3us but dur_us=15.2 -> ~8-10us of 2-node
// graph replay / launch / drain overhead.  Single node removes one launch+drain;
// zeroed lines stay in L2 (8.4 MB < 32 MB) so phase-2 atomics L2-hit.
// Scatter math unchanged from round 4 (c*d^2 <= 12 cutoff, spherical gate,
// absmax 0.031 vs threshold 0.4125).

#define EXP_CUT 12.0f
#define NBLK 1024
#define NTHR 256

__global__ __launch_bounds__(NTHR)
void fused_gauss(const float* __restrict__ coords,
                 const float* __restrict__ amps,
                 const float* __restrict__ pix,
                 const int* __restrict__ resp,
                 float* __restrict__ out,
                 int n_atoms, int n4)
{
    const int NXg = 128, NYg = 128;

    // ---- phase 1: zero the output (exactly 2 float4 per thread) ----
    float4* o4 = (float4*)out;
    for (int i = blockIdx.x * NTHR + threadIdx.x; i < n4; i += NBLK * NTHR)
        o4[i] = make_float4(0.f, 0.f, 0.f, 0.f);

    cg::this_grid().sync();

    // ---- phase 2: per-atom scatter, atoms block-strided ----
    // sigma = res/(sqrt(2) pi); c = 1/(2 sigma^2)
    const float res   = (float)resp[0];
    const float sigma = res / (sqrtf(2.0f) * 3.14159265358979323846f);
    const float c     = 1.0f / (2.0f * sigma * sigma);
    const float R     = sqrtf(EXP_CUT / c);   // ~2.2 A for res=2

    // affine grid from the actual pix_coords input (x fastest, then y, then z)
    const float ox = pix[0], oy = pix[1], oz = pix[2];
    const float sx = pix[3] - pix[0];
    const float sy = pix[NXg * 3 + 1] - pix[1];
    const float sz = pix[NXg * NYg * 3 + 2] - pix[2];

    for (int a = blockIdx.x; a < n_atoms; a += NBLK) {
        const float cx  = coords[a * 3 + 0];
        const float cy  = coords[a * 3 + 1];
        const float cz  = coords[a * 3 + 2];
        const float amp = amps[a];

        int ixlo = max(0,       (int)ceilf ((cx - R - ox) / sx));
        int ixhi = min(NXg - 1, (int)floorf((cx + R - ox) / sx));
        int iylo = max(0,       (int)ceilf ((cy - R - oy) / sy));
        int iyhi = min(NYg - 1, (int)floorf((cy + R - oy) / sy));
        int izlo = max(0,       (int)ceilf ((cz - R - oz) / sz));
        int izhi = min(127,     (int)floorf((cz + R - oz) / sz));

        const int nx = ixhi - ixlo + 1;
        const int ny = iyhi - iylo + 1;
        const int nz = izhi - izlo + 1;
        if (nx <= 0 || ny <= 0 || nz <= 0) continue;  // outside grid (uniform)

        const int tasks = nx * ny * nz;               // typically ~125-216
        for (int t = threadIdx.x; t < tasks; t += NTHR) {
            int dx = t % nx;       // x fastest -> consecutive lanes, consecutive addrs
            int r  = t / nx;
            int dy = r % ny;
            int dz = r / ny;
            float fx = ox + (float)(ixlo + dx) * sx - cx;
            float fy = oy + (float)(iylo + dy) * sy - cy;
            float fz = oz + (float)(izlo + dz) * sz - cz;
            float e  = c * (fx * fx + fy * fy + fz * fz);
            if (e <= EXP_CUT) {    // spherical gate: cube corners issue no atomic
                int idx = ((izlo + dz) * NYg + (iylo + dy)) * NXg + (ixlo + dx);
                atomicAdd(out + idx, amp * __expf(-e));
            }
        }
    }
}

extern "C" void kernel_launch(void* const* d_in, const int* in_sizes, int n_in,
                              void* d_out, int out_size, void* d_ws, size_t ws_size,
                              hipStream_t stream)
{
    const float* coords = (const float*)d_in[0];   // (3000, 3) f32
    const float* amps   = (const float*)d_in[1];   // (3000,)  f32
    const float* pix    = (const float*)d_in[2];   // (2097152, 3) f32
    const int*   resp   = (const int*)d_in[3];     // scalar int
    float* out = (float*)d_out;                    // (1,128,128,128) f32

    int n_atoms = in_sizes[1];
    int n4 = out_size / 4;                         // 2097152 floats -> 524288 float4

    // single cooperative kernel: zero -> grid.sync -> scatter.
    // 1024 blocks x 256 thr = 4 blocks/CU (16 waves/CU), co-residency validated
    // by the cooperative launch itself.
    void* args[] = {(void*)&coords, (void*)&amps, (void*)&pix, (void*)&resp,
                    (void*)&out, (void*)&n_atoms, (void*)&n4};
    hipLaunchCooperativeKernel((const void*)fused_gauss, dim3(NBLK), dim3(NTHR),
                               args, 0, stream);
}

// Round 6
// 18.439 us; speedup vs baseline: 4.3635x; 4.3635x over previous
//
#include <hip/hip_runtime.h>
#include <math.h>

// Gaussian map generator: out[z,y,x] = sum_a amp[a] * exp(-c * |r_voxel - r_atom|^2)
// c = 1/(2 sigma^2), sigma = resolution/(sqrt(2) pi).  res=2 -> c~2.467.
// Cutoff c*d^2 <= 12: neglected pair <= 16*e^-12 ~ 1e-4; measured absmax 0.031
// vs threshold 0.4125 (round 4).
//
// Round 6: ONE-node gather-by-tile (no zero pass, no global atomics, no grid sync).
//  - round 4 (zero + scatter, 2 nodes): 15.2us; decomposition suggests ~9-11us is
//    graph/launch/sync overhead -> removing a node + all atomic traffic is the
//    only lever left.
//  - round 5 (cooperative fusion): 80us -- grid.sync costs ~60us on 8 XCDs. Avoided.
// Structure: 4096 blocks x 256 thr; block owns a 32x4x4 voxel tile (x-run = 128 B
// = full cache line). Threads cull 3000 atoms against the R-expanded tile (exact
// box-sphere distance) into an LDS float4 list (worst central tile ~60-100, cap 512),
// then each thread register-accumulates 2 consecutive-x voxels over the list and
// stores once, coalesced. Same c*d^2<=12 gate as round 4 => same pair set.

#define EXP_CUT 12.0f
#define CAP     512
#define NTHR    256

__global__ __launch_bounds__(NTHR)
void gather_gauss(const float* __restrict__ coords,
                  const float* __restrict__ amps,
                  const float* __restrict__ pix,
                  const int* __restrict__ resp,
                  float* __restrict__ out,
                  int n_atoms)
{
    const int NXg = 128, NYg = 128;
    __shared__ float4 alist[CAP];   // {x, y, z, amp}
    __shared__ int    acnt;

    // tile origin in voxel indices: 4 x-tiles, 32 y-tiles, 32 z-tiles
    const int bid = blockIdx.x;
    const int tx = (bid & 3) * 32;
    const int ty = ((bid >> 2) & 31) * 4;
    const int tz = (bid >> 7) * 4;

    if (threadIdx.x == 0) acnt = 0;

    // sigma = res/(sqrt(2) pi); c = 1/(2 sigma^2)
    const float res   = (float)resp[0];
    const float sigma = res / (sqrtf(2.0f) * 3.14159265358979323846f);
    const float c     = 1.0f / (2.0f * sigma * sigma);
    const float R2    = EXP_CUT / c;         // (cutoff radius)^2, ~4.86 A^2

    // affine grid from the actual pix_coords input (x fastest, then y, then z; steps > 0)
    const float ox = pix[0], oy = pix[1], oz = pix[2];
    const float sx = pix[3] - pix[0];
    const float sy = pix[NXg * 3 + 1] - pix[1];
    const float sz = pix[NXg * NYg * 3 + 2] - pix[2];

    // tile bounds in Angstroms (voxel centers)
    const float xlo = ox + (float)tx * sx,  xhi = ox + (float)(tx + 31) * sx;
    const float ylo = oy + (float)ty * sy,  yhi = oy + (float)(ty + 3) * sy;
    const float zlo = oz + (float)tz * sz,  zhi = oz + (float)(tz + 3) * sz;

    __syncthreads();   // acnt = 0 visible

    // ---- cull: exact box-sphere distance test, survivors -> LDS list ----
    for (int a = threadIdx.x; a < n_atoms; a += NTHR) {
        float ax = coords[3 * a + 0];
        float ay = coords[3 * a + 1];
        float az = coords[3 * a + 2];
        float dx = fmaxf(fmaxf(xlo - ax, ax - xhi), 0.0f);
        float dy = fmaxf(fmaxf(ylo - ay, ay - yhi), 0.0f);
        float dz = fmaxf(fmaxf(zlo - az, az - zhi), 0.0f);
        if (dx * dx + dy * dy + dz * dz <= R2) {
            int i = atomicAdd(&acnt, 1);           // LDS atomic
            if (i < CAP) alist[i] = make_float4(ax, ay, az, amps[a]);
        }
    }
    __syncthreads();
    const int n = min(acnt, CAP);                  // worst central tile ~60-100 << 512

    // ---- accumulate: 2 consecutive-x voxels per thread, in registers ----
    const int lv = threadIdx.x * 2;                // local voxel 0..511, x fastest
    const int lx = lv & 31;
    const int ly = (lv >> 5) & 3;
    const int lz = lv >> 7;
    const float vx0 = ox + (float)(tx + lx) * sx;
    const float vx1 = vx0 + sx;
    const float vy  = oy + (float)(ty + ly) * sy;
    const float vz  = oz + (float)(tz + lz) * sz;

    float acc0 = 0.0f, acc1 = 0.0f;
    for (int s = 0; s < n; ++s) {
        float4 A = alist[s];                       // same addr all lanes -> broadcast
        float dy  = vy - A.y;
        float dz  = vz - A.z;
        float d2c = dy * dy + dz * dz;
        float dx0 = vx0 - A.x;
        float dx1 = vx1 - A.x;
        float e0  = c * (d2c + dx0 * dx0);
        float e1  = c * (d2c + dx1 * dx1);
        if (e0 <= EXP_CUT) acc0 += A.w * __expf(-e0);   // same gate as round 4
        if (e1 <= EXP_CUT) acc1 += A.w * __expf(-e1);
    }

    // ---- store: one float2 per thread; wave covers contiguous 512 B ----
    const size_t gidx = ((size_t)(tz + lz) * NYg + (size_t)(ty + ly)) * NXg + (tx + lx);
    *(float2*)(out + gidx) = make_float2(acc0, acc1);
}

extern "C" void kernel_launch(void* const* d_in, const int* in_sizes, int n_in,
                              void* d_out, int out_size, void* d_ws, size_t ws_size,
                              hipStream_t stream)
{
    const float* coords = (const float*)d_in[0];   // (3000, 3) f32
    const float* amps   = (const float*)d_in[1];   // (3000,)  f32
    const float* pix    = (const float*)d_in[2];   // (2097152, 3) f32
    const int*   resp   = (const int*)d_in[3];     // scalar int
    float* out = (float*)d_out;                    // (1,128,128,128) f32

    const int n_atoms = in_sizes[1];

    // single kernel, single graph node: every voxel computed and stored exactly once.
    gather_gauss<<<4096, NTHR, 0, stream>>>(coords, amps, pix, resp, out, n_atoms);
}